// Round 4
// baseline (106.681 us; speedup 1.0000x reference)
//
#include <hip/hip_runtime.h>
#include <hip/hip_bf16.h>
#include <math.h>

// Problem constants
#define BATCH 1024
#define X_DIM 32
#define U_DIM 8
#define PHI 128
#define HID 128

typedef float f4 __attribute__((ext_vector_type(4)));

__device__ __forceinline__ float fast_tanh(float x) {
    return 1.0f - 2.0f / (__expf(2.0f * x) + 1.0f);
}

// ---------------------------------------------------------------------------
// Fused kernel, symmetry-aware + granule-regular triangle.
// One block per batch row b, 512 threads (8 waves), wave u streams the lower
// triangle of the symmetric 128x128 tile L[b,u] rounded up to 64B granules:
// rows 16g..16g+15 each read (g+1) 64-byte blocks (cols 0..16(g+1)-1).
// Each row is owned by a 4-lane team (team = l>>2); lane covers float4 #sl
// of each 64B block. Per group g the lane's row r = 16g+team is FIXED, so
// phi[r]/Q[r] hoist out of the inner loop; phi chunks are preloaded into
// registers (compile-time index after full unroll). Elements past the
// diagonal get weight 0 (and 0.5 on the diagonal) via a lane-constant mask
// applied only at the last block of each group (the only place they occur).
//   mu[b,u] = sum_r [ Qr*S1_r + phir*S2_r ],  S1_r = sum_q w L_rq phi_q,
//                                             S2_r = sum_q w L_rq Q_q
//   sf[b,u] = 1 + 2 * sum_r phir * S1_r
// ---------------------------------------------------------------------------
__global__ __launch_bounds__(512) void fused_kernel(
    const float* __restrict__ x,
    const float* __restrict__ Q,
    const float* __restrict__ L,
    const float* __restrict__ W1, const float* __restrict__ b1,
    const float* __restrict__ W2, const float* __restrict__ b2,
    const float* __restrict__ W3, const float* __restrict__ b3,
    const float* __restrict__ W4, const float* __restrict__ b4,
    const float* __restrict__ logSigEps,
    float* __restrict__ mu_out,   // 8192 = (B,U,1)
    float* __restrict__ sig_out)  // 65536 = (B,U,U)
{
    const int b = blockIdx.x;
    const int t = threadIdx.x;     // 0..511

    __shared__ float sx[X_DIM];
    __shared__ float h[HID];
    __shared__ alignas(16) float s_phi[PHI];
    __shared__ alignas(16) float s_Q[U_DIM * PHI];   // 4KB

    // preload Q (1024 floats) with all 512 threads, and x with the first 32
    {
        const float2* Qg = (const float2*)(Q + (size_t)b * (U_DIM * PHI));
        ((float2*)s_Q)[t] = Qg[t];
    }
    if (t < X_DIM) sx[t] = x[b * X_DIM + t];
    __syncthreads();

    // ---- Phase 1: MLP on threads 0..127 ----
    float acc;
    if (t < HID) {
        acc = b1[t];
#pragma unroll
        for (int k = 0; k < X_DIM; ++k) acc += sx[k] * W1[k * HID + t];
        h[t] = fast_tanh(acc);
    }
    __syncthreads();
    if (t < HID) {
        acc = b2[t];
#pragma unroll 8
        for (int k = 0; k < HID; ++k) acc += h[k] * W2[k * HID + t];
        acc = fast_tanh(acc);
    }
    __syncthreads();
    if (t < HID) h[t] = acc;
    __syncthreads();
    if (t < HID) {
        acc = b3[t];
#pragma unroll 8
        for (int k = 0; k < HID; ++k) acc += h[k] * W3[k * HID + t];
        acc = fast_tanh(acc);
    }
    __syncthreads();
    if (t < HID) h[t] = acc;
    __syncthreads();
    if (t < HID) {
        acc = b4[t];
#pragma unroll 8
        for (int k = 0; k < HID; ++k) acc += h[k] * W4[k * HID + t];
        s_phi[t] = acc;
    }
    __syncthreads();

    // ---- Phase 2: per-wave granule-regular triangle stream ----
    const int u    = t >> 6;       // wave id = u, 0..7
    const int l    = t & 63;       // lane
    const int team = l >> 2;       // 0..15: row owner within each 16-row group
    const int sl   = l & 3;        // float4 slot within the 64B block

    const float* __restrict__ Qu  = s_Q + u * PHI;
    const f4*    __restrict__ s_phi4 = (const f4*)s_phi;
    const f4*    __restrict__ Qu4    = (const f4*)Qu;

    const char* __restrict__ lane_base =
        (const char*)(L + ((size_t)(b * U_DIM + u)) * (PHI * PHI))
        + team * 512 + sl * 16;

    // preload the 8 possible phi chunks (c = 4j+sl) into registers
    f4 phr[8];
#pragma unroll
    for (int j = 0; j < 8; ++j) phr[j] = s_phi4[4 * j + sl];

    // lane-constant diagonal/past-diagonal weight mask: d = 4*sl+e - team
    f4 wm;
    {
        const int d0 = 4 * sl - team;
        wm.x = (d0 + 0 < 0) ? 1.0f : ((d0 + 0 == 0) ? 0.5f : 0.0f);
        wm.y = (d0 + 1 < 0) ? 1.0f : ((d0 + 1 == 0) ? 0.5f : 0.0f);
        wm.z = (d0 + 2 < 0) ? 1.0f : ((d0 + 2 == 0) ? 0.5f : 0.0f);
        wm.w = (d0 + 3 < 0) ? 1.0f : ((d0 + 3 == 0) ? 0.5f : 0.0f);
    }

    float accm = 0.0f, accf = 0.0f;
#pragma unroll
    for (int g = 0; g < 8; ++g) {
        const int r = 16 * g + team;
        const float phir = s_phi[r];
        const float Qr   = Qu[r];
        float S1 = 0.0f, S2 = 0.0f;
#pragma unroll
        for (int j = 0; j <= g; ++j) {
            f4 v = __builtin_nontemporal_load(
                (const f4*)(lane_base + g * 8192 + j * 64));
            if (j == g) v *= wm;                 // wave-uniform, compile-time
            const f4 ph = phr[j];
            const f4 qv = Qu4[4 * j + sl];
            S1 += v.x * ph.x + v.y * ph.y + v.z * ph.z + v.w * ph.w;
            S2 += v.x * qv.x + v.y * qv.y + v.z * qv.z + v.w * qv.w;
        }
        accm += Qr * S1 + phir * S2;
        accf += phir * S1;
    }

    // intra-wave butterfly reduction (64 lanes)
#pragma unroll
    for (int off = 1; off < 64; off <<= 1) {
        accm += __shfl_xor(accm, off);
        accf += __shfl_xor(accf, off);
    }

    const int bu = b * U_DIM + u;
    if (l == 0) mu_out[bu] = accm;
    if (l < U_DIM) {
        const float sf = 1.0f + 2.0f * accf;
        sig_out[(size_t)bu * U_DIM + l] = (l == u) ? __expf(logSigEps[u]) * sf : 0.0f;
    }
}

extern "C" void kernel_launch(void* const* d_in, const int* in_sizes, int n_in,
                              void* d_out, int out_size, void* d_ws, size_t ws_size,
                              hipStream_t stream)
{
    const float* x         = (const float*)d_in[0];
    const float* Q         = (const float*)d_in[1];
    const float* L         = (const float*)d_in[2];
    const float* W1        = (const float*)d_in[3];
    const float* b1        = (const float*)d_in[4];
    const float* W2        = (const float*)d_in[5];
    const float* b2        = (const float*)d_in[6];
    const float* W3        = (const float*)d_in[7];
    const float* b3        = (const float*)d_in[8];
    const float* W4        = (const float*)d_in[9];
    const float* b4        = (const float*)d_in[10];
    const float* logSigEps = (const float*)d_in[11];

    float* out     = (float*)d_out;
    float* mu_out  = out;                   // 8192
    float* sig_out = out + BATCH * U_DIM;   // 65536

    fused_kernel<<<BATCH, 512, 0, stream>>>(x, Q, L,
                                            W1, b1, W2, b2, W3, b3, W4, b4,
                                            logSigEps, mu_out, sig_out);
}

// Round 5
// 94.459 us; speedup vs baseline: 1.1294x; 1.1294x over previous
//
#include <hip/hip_runtime.h>
#include <hip/hip_bf16.h>
#include <math.h>

// Problem constants
#define BATCH 1024
#define X_DIM 32
#define U_DIM 8
#define PHI 128
#define HID 128

typedef float f4 __attribute__((ext_vector_type(4)));

__device__ __forceinline__ float fast_tanh(float x) {
    return 1.0f - 2.0f / (__expf(2.0f * x) + 1.0f);
}

// ---------------------------------------------------------------------------
// Fused kernel, symmetry-aware, granule-regular triangle, ZERO in-loop LDS.
// One block per batch row b, 512 threads (8 waves), wave u streams the lower
// triangle of the symmetric 128x128 tile L[b,u] rounded to 64B granules:
// rows 16g..16g+15 read (g+1) 64-byte blocks each (cols 0..16(g+1)-1).
// lane = (team = l>>2 -> row within group, sl = l&3 -> float4 slot in block).
// ALL phi/Q operands are preloaded into registers before the loop (indices
// are affine in (g, j, lane) and compile-time after full unroll):
//   phr[j]  = phi float4 chunk 4j+sl        (A-side of row dot)
//   qvr[j]  = Q   float4 chunk 4j+sl
//   phir[g] = phi[16g+team],  qr[g] = Q[16g+team]
// Hot loop body: 1 global_load_dwordx4 + 8 FMA + 2 FMA-accum. Plain (cached)
// loads so the 64B half-lines merge in L2 across adjacent j iterations.
// Diagonal/past-diagonal weights (1 / 0.5 / 0) enter only at block j==g via
// the lane-constant mask wm.
//   mu[b,u] = sum_r [ Qr*S1_r + phir*S2_r ],  S1_r = sum_q w L_rq phi_q,
//                                             S2_r = sum_q w L_rq Q_q
//   sf[b,u] = 1 + 2 * sum_r phir * S1_r
// ---------------------------------------------------------------------------
__global__ __launch_bounds__(512, 4) void fused_kernel(
    const float* __restrict__ x,
    const float* __restrict__ Q,
    const float* __restrict__ L,
    const float* __restrict__ W1, const float* __restrict__ b1,
    const float* __restrict__ W2, const float* __restrict__ b2,
    const float* __restrict__ W3, const float* __restrict__ b3,
    const float* __restrict__ W4, const float* __restrict__ b4,
    const float* __restrict__ logSigEps,
    float* __restrict__ mu_out,   // 8192 = (B,U,1)
    float* __restrict__ sig_out)  // 65536 = (B,U,U)
{
    const int b = blockIdx.x;
    const int t = threadIdx.x;     // 0..511

    __shared__ float sx[X_DIM];
    __shared__ float h[HID];
    __shared__ alignas(16) float s_phi[PHI];
    __shared__ alignas(16) float s_Q[U_DIM * PHI];   // 4KB

    // preload Q (1024 floats) with all 512 threads, and x with the first 32
    {
        const float2* Qg = (const float2*)(Q + (size_t)b * (U_DIM * PHI));
        ((float2*)s_Q)[t] = Qg[t];
    }
    if (t < X_DIM) sx[t] = x[b * X_DIM + t];
    __syncthreads();

    // ---- Phase 1: MLP on threads 0..127 ----
    float acc;
    if (t < HID) {
        acc = b1[t];
#pragma unroll
        for (int k = 0; k < X_DIM; ++k) acc += sx[k] * W1[k * HID + t];
        h[t] = fast_tanh(acc);
    }
    __syncthreads();
    if (t < HID) {
        acc = b2[t];
#pragma unroll 8
        for (int k = 0; k < HID; ++k) acc += h[k] * W2[k * HID + t];
        acc = fast_tanh(acc);
    }
    __syncthreads();
    if (t < HID) h[t] = acc;
    __syncthreads();
    if (t < HID) {
        acc = b3[t];
#pragma unroll 8
        for (int k = 0; k < HID; ++k) acc += h[k] * W3[k * HID + t];
        acc = fast_tanh(acc);
    }
    __syncthreads();
    if (t < HID) h[t] = acc;
    __syncthreads();
    if (t < HID) {
        acc = b4[t];
#pragma unroll 8
        for (int k = 0; k < HID; ++k) acc += h[k] * W4[k * HID + t];
        s_phi[t] = acc;
    }
    __syncthreads();

    // ---- Phase 2: per-wave granule-regular triangle stream, LDS-free loop --
    const int u    = t >> 6;       // wave id = u, 0..7
    const int l    = t & 63;       // lane
    const int team = l >> 2;       // 0..15: row owner within each 16-row group
    const int sl   = l & 3;        // float4 slot within the 64B block

    const float* __restrict__ Qu     = s_Q + u * PHI;
    const f4*    __restrict__ s_phi4 = (const f4*)s_phi;
    const f4*    __restrict__ Qu4    = (const f4*)Qu;

    const char* __restrict__ lane_base =
        (const char*)(L + ((size_t)(b * U_DIM + u)) * (PHI * PHI))
        + team * 512 + sl * 16;

    // hoist ALL LDS operands into registers (compile-time indices after unroll)
    f4 phr[8], qvr[8];
#pragma unroll
    for (int j = 0; j < 8; ++j) {
        phr[j] = s_phi4[4 * j + sl];
        qvr[j] = Qu4[4 * j + sl];
    }
    float phir[8], qr[8];
#pragma unroll
    for (int g = 0; g < 8; ++g) {
        phir[g] = s_phi[16 * g + team];
        qr[g]   = Qu[16 * g + team];
    }

    // lane-constant diagonal/past-diagonal weight mask: d = 4*sl+k - team
    f4 wm;
    {
        const int d0 = 4 * sl - team;
        wm.x = (d0 + 0 < 0) ? 1.0f : ((d0 + 0 == 0) ? 0.5f : 0.0f);
        wm.y = (d0 + 1 < 0) ? 1.0f : ((d0 + 1 == 0) ? 0.5f : 0.0f);
        wm.z = (d0 + 2 < 0) ? 1.0f : ((d0 + 2 == 0) ? 0.5f : 0.0f);
        wm.w = (d0 + 3 < 0) ? 1.0f : ((d0 + 3 == 0) ? 0.5f : 0.0f);
    }

    float accm = 0.0f, accf = 0.0f;
#pragma unroll
    for (int g = 0; g < 8; ++g) {
        const char* __restrict__ gbase = lane_base + g * 8192;
        float S1 = 0.0f, S2 = 0.0f;
#pragma unroll
        for (int j = 0; j <= g; ++j) {
            f4 v = *(const f4*)(gbase + j * 64);   // cached: half-lines merge in L2
            if (j == g) v *= wm;                   // wave-uniform, compile-time
            const f4 ph = phr[j];
            const f4 qv = qvr[j];
            S1 += v.x * ph.x + v.y * ph.y + v.z * ph.z + v.w * ph.w;
            S2 += v.x * qv.x + v.y * qv.y + v.z * qv.z + v.w * qv.w;
        }
        accm += qr[g] * S1 + phir[g] * S2;
        accf += phir[g] * S1;
    }

    // intra-wave butterfly reduction (64 lanes)
#pragma unroll
    for (int off = 1; off < 64; off <<= 1) {
        accm += __shfl_xor(accm, off);
        accf += __shfl_xor(accf, off);
    }

    const int bu = b * U_DIM + u;
    if (l == 0) mu_out[bu] = accm;
    if (l < U_DIM) {
        const float sf = 1.0f + 2.0f * accf;
        sig_out[(size_t)bu * U_DIM + l] = (l == u) ? __expf(logSigEps[u]) * sf : 0.0f;
    }
}

extern "C" void kernel_launch(void* const* d_in, const int* in_sizes, int n_in,
                              void* d_out, int out_size, void* d_ws, size_t ws_size,
                              hipStream_t stream)
{
    const float* x         = (const float*)d_in[0];
    const float* Q         = (const float*)d_in[1];
    const float* L         = (const float*)d_in[2];
    const float* W1        = (const float*)d_in[3];
    const float* b1        = (const float*)d_in[4];
    const float* W2        = (const float*)d_in[5];
    const float* b2        = (const float*)d_in[6];
    const float* W3        = (const float*)d_in[7];
    const float* b3        = (const float*)d_in[8];
    const float* W4        = (const float*)d_in[9];
    const float* b4        = (const float*)d_in[10];
    const float* logSigEps = (const float*)d_in[11];

    float* out     = (float*)d_out;
    float* mu_out  = out;                   // 8192
    float* sig_out = out + BATCH * U_DIM;   // 65536

    fused_kernel<<<BATCH, 512, 0, stream>>>(x, Q, L,
                                            W1, b1, W2, b2, W3, b3, W4, b4,
                                            logSigEps, mu_out, sig_out);
}